// Round 8
// baseline (1867.247 us; speedup 1.0000x reference)
//
#include <hip/hip_runtime.h>
#include <math.h>

// FeatureWeightNet: grid_sample(bilinear,border) -> group correlation (G=8) ->
// MLP(8->16->8->1) with per-batch BN stats -> sigmoid.
// R8: SINGLE persistent kernel. R7 accounting: ~115 us of kernel work vs
// 260 us total -> ~30 us per-dispatch overhead dominates. Phases
// (transpose / sample / stats1 / stats2 / final) separated by software grid
// barriers (device-scope atomics + fences; hipLaunchCooperativeKernel proved
// unreliable in R3). Co-residency guarantee: 768 blocks <= 1024 capacity
// from __launch_bounds__(256,4); VGPR cap 128 >> phase needs (R4 lesson).
// Sample phase keeps R7's proven pure-gather body (3.7 TB/s) untouched.

constexpr int   Bc  = 2;
constexpr int   Cc  = 64;
constexpr int   Hc  = 256;
constexpr int   Wc  = 320;
constexpr int   NBc = 9;
constexpr int   HWc = Hc * Wc;            // 81920
constexpr int   NPIX = Bc * HWc;          // 163840
constexpr int   NPT  = Bc * NBc * HWc;    // 1474560 (= out_size)
constexpr float EPSV = 1e-5f;

constexpr int NBLKS = 768;                // <= 1024 co-resident capacity
constexpr int NTILE = Bc * (HWc / 64);    // 2560 transpose tiles
constexpr int NVB   = NPIX / 32;          // 5120 virtual sample blocks
constexpr int READY = 0x1357ACE1;

// workspace layout in float units (~45 MB)
constexpr size_t OFF_FEATB = 0;                               // NHWC bf16: NPIX*64 ushort
constexpr size_t OFF_SB    = OFF_FEATB + (size_t)NPIX * 32;   // s bf16: NPT*8 ushort
constexpr size_t OFF_MOM   = OFF_SB + (size_t)NPT * 4;        // ymom[32], zmom[16]
constexpr size_t OFF_BAR   = OFF_MOM + 48;                    // 16 ints barrier state

__device__ __forceinline__ unsigned short f2bf_rne(float v) {
  unsigned int u = __float_as_uint(v);
  unsigned int r = (u + 0x7fffu + ((u >> 16) & 1u)) >> 16;
  return (unsigned short)r;
}
__device__ __forceinline__ void unpack8(uint4 u, float f[8]) {
  f[0] = __uint_as_float(u.x << 16);
  f[1] = __uint_as_float(u.x & 0xffff0000u);
  f[2] = __uint_as_float(u.y << 16);
  f[3] = __uint_as_float(u.y & 0xffff0000u);
  f[4] = __uint_as_float(u.z << 16);
  f[5] = __uint_as_float(u.z & 0xffff0000u);
  f[6] = __uint_as_float(u.w << 16);
  f[7] = __uint_as_float(u.w & 0xffff0000u);
}

// software grid barrier k (cnt = bar[k], flag = bar[4+k]); all NBLKS blocks
// co-resident by construction.  Release/acquire at agent (device) scope.
__device__ __forceinline__ void grid_barrier(int* bar, int k) {
  __syncthreads();
  if (threadIdx.x == 0) {
    __threadfence();  // release: drain this XCD's prior writes
    const int a = __hip_atomic_fetch_add(&bar[k], 1, __ATOMIC_ACQ_REL,
                                         __HIP_MEMORY_SCOPE_AGENT);
    if (a == NBLKS - 1) {
      __hip_atomic_store(&bar[4 + k], 1, __ATOMIC_RELEASE,
                         __HIP_MEMORY_SCOPE_AGENT);
    } else {
      while (__hip_atomic_load(&bar[4 + k], __ATOMIC_ACQUIRE,
                               __HIP_MEMORY_SCOPE_AGENT) == 0) {
        __builtin_amdgcn_s_sleep(2);
      }
    }
    __threadfence();  // acquire: invalidate stale cache lines
  }
  __syncthreads();
}

// ---------------------------------------------------------------------------
__global__ __launch_bounds__(256, 4) void k_all(
    const float* __restrict__ feat, const float* __restrict__ grid,
    const float* __restrict__ w0, const float* __restrict__ g0,
    const float* __restrict__ b0, const float* __restrict__ w1,
    const float* __restrict__ g1, const float* __restrict__ b1,
    const float* __restrict__ wsW, const float* __restrict__ bs,
    unsigned short* __restrict__ featB, unsigned short* __restrict__ sB,
    float* __restrict__ mom, int* __restrict__ bar,
    float* __restrict__ out) {
  __shared__ float lds[64][65];
  __shared__ float w0s[128], w1s[128], a1s[16], c1s[16], a2s[8], c2s[8], wss[8];
  __shared__ float bssS;
  __shared__ float red[128];

  const int tid = threadIdx.x;
  const int blk = blockIdx.x;
  float* ymom = mom;       // [32]
  float* zmom = mom + 32;  // [16]

  // ---- init gate: block 0 zeroes barrier state + moment slots (ws is
  // poisoned 0xAA each call), then opens the gate ----
  if (blk == 0) {
    if (tid < 8) bar[tid] = 0;
    if (tid < 48) mom[tid] = 0.f;
    __syncthreads();
    if (tid == 0) {
      __threadfence();
      __hip_atomic_store(&bar[8], READY, __ATOMIC_RELEASE,
                         __HIP_MEMORY_SCOPE_AGENT);
    }
  }
  if (tid < 128) { w0s[tid] = w0[tid]; w1s[tid] = w1[tid]; }

  // ---- Phase A: NCHW fp32 -> NHWC bf16 transpose, grid-stride over tiles ----
  for (int t = blk; t < NTILE; t += NBLKS) {
    const int b    = t / (HWc / 64);
    const int hw0  = (t % (HWc / 64)) * 64;
    const int p    = tid & 63;
    const int ty   = tid >> 6;  // 0..3
    __syncthreads();            // lds reuse guard
    const float* src = feat + (size_t)b * Cc * HWc + hw0 + p;
#pragma unroll
    for (int c0 = 0; c0 < 64; c0 += 4) {
      lds[c0 + ty][p] = src[(size_t)(c0 + ty) * HWc];
    }
    __syncthreads();
    const int ch = tid & 63;
    unsigned short* dst = featB + ((size_t)b * HWc + hw0) * 64 + ch;
#pragma unroll
    for (int p0 = 0; p0 < 64; p0 += 4) {
      dst[(size_t)(p0 + ty) * 64] = f2bf_rne(lds[ch][p0 + ty]);
    }
  }

  // gate (all blocks must see initialized barrier state before arriving)
  if (tid == 0 && blk != 0) {
    while (__hip_atomic_load(&bar[8], __ATOMIC_ACQUIRE,
                             __HIP_MEMORY_SCOPE_AGENT) != READY) {
      __builtin_amdgcn_s_sleep(2);
    }
  }
  grid_barrier(bar, 0);

  // ---- Phase B: grid sample + group correlation (R7's proven pure body) ----
  const uint4* fbAll = (const uint4*)featB;
  for (int vb = blk; vb < NVB; vb += NBLKS) {
    const int cid = vb * 32 + (tid >> 3);
    const int j   = tid & 7;
    const int b   = cid / HWc;
    const int hw  = cid - b * HWc;
    const int h   = hw / Wc;
    const int w   = hw - h * Wc;

    const uint4 ur = fbAll[(size_t)cid * 8 + j];
    float r[8];
    unpack8(ur, r);
    const uint4* fb = fbAll + (size_t)b * HWc * 8;

#pragma unroll 3
    for (int n = 0; n < NBc; ++n) {
      const size_t gi = ((((size_t)b * NBc + n) * Hc + h) * Wc + w) * 2;
      const float2 g2 = *(const float2*)(grid + gi);
      float ix = ((g2.x + 1.f) * (float)Wc - 1.f) * 0.5f;
      float iy = ((g2.y + 1.f) * (float)Hc - 1.f) * 0.5f;
      ix = fminf(fmaxf(ix, 0.f), (float)(Wc - 1));
      iy = fminf(fmaxf(iy, 0.f), (float)(Hc - 1));
      const float x0f = floorf(ix), y0f = floorf(iy);
      const float fx = ix - x0f, fy = iy - y0f;
      const int x0 = (int)x0f, y0 = (int)y0f;
      const int x1 = min(x0 + 1, Wc - 1), y1 = min(y0 + 1, Hc - 1);
      const float w00 = (1.f - fx) * (1.f - fy);
      const float w01 = fx * (1.f - fy);
      const float w10 = (1.f - fx) * fy;
      const float w11 = fx * fy;

      const uint4 u00 = fb[(size_t)(y0 * Wc + x0) * 8 + j];
      const uint4 u01 = fb[(size_t)(y0 * Wc + x1) * 8 + j];
      const uint4 u10 = fb[(size_t)(y1 * Wc + x0) * 8 + j];
      const uint4 u11 = fb[(size_t)(y1 * Wc + x1) * 8 + j];
      float a[8], c[8], d[8], e[8];
      unpack8(u00, a);
      unpack8(u01, c);
      unpack8(u10, d);
      unpack8(u11, e);

      float s = 0.f;
#pragma unroll
      for (int k = 0; k < 8; ++k) {
        s += (w00 * a[k] + w01 * c[k] + w10 * d[k] + w11 * e[k]) * r[k];
      }
      s *= 0.125f;  // mean over C/G = 8

      const size_t pt = ((size_t)b * NBc + n) * HWc + hw;
      sB[pt * 8 + j] = f2bf_rne(s);
    }
  }
  grid_barrier(bar, 1);

  // ---- Phase C: stats1 — y/y^2 sums (y = w0 @ s) -> ymom[32] ----
  {
    float sy[16], sy2[16];
#pragma unroll
    for (int c = 0; c < 16; ++c) { sy[c] = 0.f; sy2[c] = 0.f; }
    const int stride = NBLKS * 256;
    for (int p = blk * 256 + tid; p < NPT; p += stride) {
      const uint4 su = ((const uint4*)sB)[p];
      float s[8];
      unpack8(su, s);
#pragma unroll
      for (int c = 0; c < 16; ++c) {
        const float* wr = w0s + c * 8;
        float y = 0.f;
#pragma unroll
        for (int k = 0; k < 8; ++k) y += wr[k] * s[k];
        sy[c] += y;
        sy2[c] += y * y;
      }
    }
#pragma unroll
    for (int c = 0; c < 16; ++c) {
      for (int off = 32; off >= 1; off >>= 1) {
        sy[c] += __shfl_xor(sy[c], off);
        sy2[c] += __shfl_xor(sy2[c], off);
      }
    }
    const int wid = tid >> 6;
    if ((tid & 63) == 0) {
#pragma unroll
      for (int c = 0; c < 16; ++c) {
        red[wid * 32 + c] = sy[c];
        red[wid * 32 + 16 + c] = sy2[c];
      }
    }
    __syncthreads();
    if (tid < 32) {
      atomicAdd(&ymom[tid],
                red[tid] + red[32 + tid] + red[64 + tid] + red[96 + tid]);
    }
  }
  grid_barrier(bar, 2);

  // ---- Phase D: stats2 — bn1 from ymom; z/z^2 -> zmom[16] ----
  if (tid < 16) {
    const float invN = 1.f / (float)NPT;
    const float mean = ymom[tid] * invN;
    const float var = ymom[16 + tid] * invN - mean * mean;
    const float a = g0[tid] * rsqrtf(var + EPSV);
    a1s[tid] = a;
    c1s[tid] = b0[tid] - mean * a;
  }
  __syncthreads();
  {
    float sz[8], sz2[8];
#pragma unroll
    for (int o = 0; o < 8; ++o) { sz[o] = 0.f; sz2[o] = 0.f; }
    const int stride = NBLKS * 256;
    for (int p = blk * 256 + tid; p < NPT; p += stride) {
      const uint4 su = ((const uint4*)sB)[p];
      float s[8];
      unpack8(su, s);
      float x1[16];
#pragma unroll
      for (int c = 0; c < 16; ++c) {
        const float* wr = w0s + c * 8;
        float y = 0.f;
#pragma unroll
        for (int k = 0; k < 8; ++k) y += wr[k] * s[k];
        x1[c] = fmaxf(a1s[c] * y + c1s[c], 0.f);
      }
#pragma unroll
      for (int o = 0; o < 8; ++o) {
        const float* wr = w1s + o * 16;
        float z = 0.f;
#pragma unroll
        for (int k = 0; k < 16; ++k) z += wr[k] * x1[k];
        sz[o] += z;
        sz2[o] += z * z;
      }
    }
#pragma unroll
    for (int o = 0; o < 8; ++o) {
      for (int off = 32; off >= 1; off >>= 1) {
        sz[o] += __shfl_xor(sz[o], off);
        sz2[o] += __shfl_xor(sz2[o], off);
      }
    }
    __syncthreads();  // red reuse guard
    const int wid = tid >> 6;
    if ((tid & 63) == 0) {
#pragma unroll
      for (int o = 0; o < 8; ++o) {
        red[wid * 16 + o] = sz[o];
        red[wid * 16 + 8 + o] = sz2[o];
      }
    }
    __syncthreads();
    if (tid < 16) {
      atomicAdd(&zmom[tid],
                red[tid] + red[16 + tid] + red[32 + tid] + red[48 + tid]);
    }
  }
  grid_barrier(bar, 3);

  // ---- Phase E: final — bn2 from zmom; MLP + sigmoid -> out ----
  if (tid < 8) {
    const float invN = 1.f / (float)NPT;
    const float mean = zmom[tid] * invN;
    const float var = zmom[8 + tid] * invN - mean * mean;
    const float a = g1[tid] * rsqrtf(var + EPSV);
    a2s[tid] = a;
    c2s[tid] = b1[tid] - mean * a;
    wss[tid] = wsW[tid];
  }
  if (tid == 0) bssS = bs[0];
  __syncthreads();
  {
    const int stride = NBLKS * 256;
    for (int p = blk * 256 + tid; p < NPT; p += stride) {
      const uint4 su = ((const uint4*)sB)[p];
      float s[8];
      unpack8(su, s);
      float x1[16];
#pragma unroll
      for (int c = 0; c < 16; ++c) {
        const float* wr = w0s + c * 8;
        float y = 0.f;
#pragma unroll
        for (int k = 0; k < 8; ++k) y += wr[k] * s[k];
        x1[c] = fmaxf(a1s[c] * y + c1s[c], 0.f);
      }
      float o = bssS;
#pragma unroll
      for (int oc = 0; oc < 8; ++oc) {
        const float* wr = w1s + oc * 16;
        float z = 0.f;
#pragma unroll
        for (int k = 0; k < 16; ++k) z += wr[k] * x1[k];
        const float x2 = fmaxf(a2s[oc] * z + c2s[oc], 0.f);
        o += wss[oc] * x2;
      }
      out[p] = 1.f / (1.f + expf(-o));
    }
  }
}

// ---------------------------------------------------------------------------
extern "C" void kernel_launch(void* const* d_in, const int* in_sizes, int n_in,
                              void* d_out, int out_size, void* d_ws,
                              size_t ws_size, hipStream_t stream) {
  const float* feat = (const float*)d_in[0];  // [2,64,256,320]
  const float* grid = (const float*)d_in[1];  // [2,2304,320,2]
  const float* w0 = (const float*)d_in[2];    // [16,8]
  const float* g0 = (const float*)d_in[3];
  const float* b0 = (const float*)d_in[4];
  const float* w1 = (const float*)d_in[5];    // [8,16]
  const float* g1 = (const float*)d_in[6];
  const float* b1 = (const float*)d_in[7];
  const float* wsW = (const float*)d_in[8];   // [1,8]
  const float* bs = (const float*)d_in[9];    // [1]
  float* out = (float*)d_out;

  float* wsf = (float*)d_ws;  // ~45 MB
  unsigned short* featB = (unsigned short*)(wsf + OFF_FEATB);
  unsigned short* sB    = (unsigned short*)(wsf + OFF_SB);
  float* mom = wsf + OFF_MOM;
  int*   bar = (int*)(wsf + OFF_BAR);

  k_all<<<NBLKS, 256, 0, stream>>>(feat, grid, w0, g0, b0, w1, g1, b1, wsW, bs,
                                   featB, sB, mom, bar, out);
}

// Round 10
// 1287.704 us; speedup vs baseline: 1.4501x; 1.4501x over previous
//
#include <hip/hip_runtime.h>
#include <math.h>

// FeatureWeightNet: grid_sample(bilinear,border) -> group correlation (G=8) ->
// MLP(8->16->8->1) with per-batch BN stats -> sigmoid.
// R10: R9 structure (3 dispatches) with the two hang fixes:
//   1. k_post gets __launch_bounds__(256,4): R9 omitted it, compiler
//      ballooned VGPR, capacity < grid -> spin deadlock. R8 proved this
//      exact phase code runs at VGPR=64 under (256,4) with 768 blocks.
//      Grid 512 for 2x co-residency margin.
//   2. Unsigned spin compare: 0xAA ws-poison reads as huge unsigned ->
//      standalone rocprof replay falls through instead of hanging.
// Mini-barrier: only atomic-written scalars (ymom/zmom) cross it — no
// __threadfence (R8 lesson: threadfence storm = 7x regression).

constexpr int   Bc  = 2;
constexpr int   Cc  = 64;
constexpr int   Hc  = 256;
constexpr int   Wc  = 320;
constexpr int   NBc = 9;
constexpr int   HWc = Hc * Wc;            // 81920
constexpr int   NPIX = Bc * HWc;          // 163840
constexpr int   NPT  = Bc * NBc * HWc;    // 1474560 (= out_size)
constexpr float EPSV = 1e-5f;

constexpr int NBLK_S = NPIX / 32;         // 5120 sample blocks
constexpr int NBLK_P = 512;               // k_post blocks (<= 1024 capacity @ VGPR cap 128)

// workspace layout in float units (~45 MB)
constexpr size_t OFF_FEATB = 0;                               // NHWC bf16: NPIX*64 ushort
constexpr size_t OFF_SB    = OFF_FEATB + (size_t)NPIX * 32;   // s bf16: NPT*8 ushort
constexpr size_t OFF_MOM   = OFF_SB + (size_t)NPT * 4;        // ymom[32], zmom[16]
constexpr size_t OFF_CNT   = OFF_MOM + 48;                    // 2 int counters

__device__ __forceinline__ unsigned short f2bf_rne(float v) {
  unsigned int u = __float_as_uint(v);
  unsigned int r = (u + 0x7fffu + ((u >> 16) & 1u)) >> 16;
  return (unsigned short)r;
}
__device__ __forceinline__ void unpack8(uint4 u, float f[8]) {
  f[0] = __uint_as_float(u.x << 16);
  f[1] = __uint_as_float(u.x & 0xffff0000u);
  f[2] = __uint_as_float(u.y << 16);
  f[3] = __uint_as_float(u.y & 0xffff0000u);
  f[4] = __uint_as_float(u.z << 16);
  f[5] = __uint_as_float(u.z & 0xffff0000u);
  f[6] = __uint_as_float(u.w << 16);
  f[7] = __uint_as_float(u.w & 0xffff0000u);
}

// Light grid barrier: release-increment, relaxed spin (UNSIGNED compare so
// poison falls through), one acquire load. No threadfence — only the
// atomic-written moment scalars cross this barrier.
__device__ __forceinline__ void mini_barrier(int* cnt) {
  __syncthreads();
  if (threadIdx.x == 0) {
    __hip_atomic_fetch_add(cnt, 1, __ATOMIC_RELEASE, __HIP_MEMORY_SCOPE_AGENT);
    while ((unsigned)__hip_atomic_load(cnt, __ATOMIC_RELAXED,
                                       __HIP_MEMORY_SCOPE_AGENT) <
           (unsigned)NBLK_P) {
      __builtin_amdgcn_s_sleep(8);
    }
    (void)__hip_atomic_load(cnt, __ATOMIC_ACQUIRE, __HIP_MEMORY_SCOPE_AGENT);
  }
  __syncthreads();
}

// ---------------------------------------------------------------------------
// K0: NCHW fp32 -> NHWC bf16 transpose; block 0 zeroes moment + counter slots.
__global__ __launch_bounds__(256) void k_transpose(
    const float* __restrict__ feat, unsigned short* __restrict__ featB,
    float* __restrict__ mom) {
  if (blockIdx.x == 0 && threadIdx.x < 56) mom[threadIdx.x] = 0.f;
  __shared__ float lds[64][65];
  const int tid  = threadIdx.x;
  const int b    = blockIdx.x / (HWc / 64);
  const int tile = blockIdx.x % (HWc / 64);
  const int hw0  = tile * 64;
  const int p    = tid & 63;
  const int ty   = tid >> 6;  // 0..3

  const float* src = feat + (size_t)b * Cc * HWc + hw0 + p;
#pragma unroll
  for (int c0 = 0; c0 < 64; c0 += 4) {
    lds[c0 + ty][p] = src[(size_t)(c0 + ty) * HWc];
  }
  __syncthreads();
  const int ch = tid & 63;
  unsigned short* dst = featB + ((size_t)b * HWc + hw0) * 64 + ch;
#pragma unroll
  for (int p0 = 0; p0 < 64; p0 += 4) {
    dst[(size_t)(p0 + ty) * 64] = f2bf_rne(lds[ch][p0 + ty]);
  }
}

// ---------------------------------------------------------------------------
// K1: grid sample + group correlation.  VERBATIM R7 (79 us, 3.7 TB/s proven).
__global__ __launch_bounds__(256) void k_sample(
    const float* __restrict__ grid, const unsigned short* __restrict__ featB,
    unsigned short* __restrict__ sOut) {
  const int tid = threadIdx.x;
  const int cid = blockIdx.x * 32 + (tid >> 3);  // pixel id in [0, NPIX)
  const int j   = tid & 7;                       // group
  const int b   = cid / HWc;
  const int hw  = cid - b * HWc;
  const int h   = hw / Wc;
  const int w   = hw - h * Wc;

  const uint4* fbAll = (const uint4*)featB;
  const uint4 ur = fbAll[(size_t)cid * 8 + j];
  float r[8];
  unpack8(ur, r);

  const uint4* fb = fbAll + (size_t)b * HWc * 8;

#pragma unroll 3
  for (int n = 0; n < NBc; ++n) {
    const size_t gi = ((((size_t)b * NBc + n) * Hc + h) * Wc + w) * 2;
    const float2 g2 = *(const float2*)(grid + gi);
    float ix = ((g2.x + 1.f) * (float)Wc - 1.f) * 0.5f;
    float iy = ((g2.y + 1.f) * (float)Hc - 1.f) * 0.5f;
    ix = fminf(fmaxf(ix, 0.f), (float)(Wc - 1));
    iy = fminf(fmaxf(iy, 0.f), (float)(Hc - 1));
    const float x0f = floorf(ix), y0f = floorf(iy);
    const float fx = ix - x0f, fy = iy - y0f;
    const int x0 = (int)x0f, y0 = (int)y0f;
    const int x1 = min(x0 + 1, Wc - 1), y1 = min(y0 + 1, Hc - 1);
    const float w00 = (1.f - fx) * (1.f - fy);
    const float w01 = fx * (1.f - fy);
    const float w10 = (1.f - fx) * fy;
    const float w11 = fx * fy;

    const uint4 u00 = fb[(size_t)(y0 * Wc + x0) * 8 + j];
    const uint4 u01 = fb[(size_t)(y0 * Wc + x1) * 8 + j];
    const uint4 u10 = fb[(size_t)(y1 * Wc + x0) * 8 + j];
    const uint4 u11 = fb[(size_t)(y1 * Wc + x1) * 8 + j];
    float a[8], c[8], d[8], e[8];
    unpack8(u00, a);
    unpack8(u01, c);
    unpack8(u10, d);
    unpack8(u11, e);

    float s = 0.f;
#pragma unroll
    for (int k = 0; k < 8; ++k) {
      s += (w00 * a[k] + w01 * c[k] + w10 * d[k] + w11 * e[k]) * r[k];
    }
    s *= 0.125f;  // mean over C/G = 8

    const size_t pt = ((size_t)b * NBc + n) * HWc + hw;
    sOut[pt * 8 + j] = f2bf_rne(s);
  }
}

// ---------------------------------------------------------------------------
// K2: fused stats1 / stats2 / final with two mini-barriers.
// (256,4): VGPR cap 128 — R8 measured this phase code at VGPR=64, no spill.
__global__ __launch_bounds__(256, 4) void k_post(
    const unsigned short* __restrict__ sB, const float* __restrict__ w0,
    const float* __restrict__ w1, const float* __restrict__ g0,
    const float* __restrict__ b0, const float* __restrict__ g1,
    const float* __restrict__ b1, const float* __restrict__ wsW,
    const float* __restrict__ bs, float* __restrict__ mom,
    int* __restrict__ cnt, float* __restrict__ out) {
  __shared__ float w0s[128], w1s[128], a1s[16], c1s[16], a2s[8], c2s[8], wss[8];
  __shared__ float bssS;
  __shared__ float red[128];
  const int tid = threadIdx.x;
  const int blk = blockIdx.x;
  const int stride = NBLK_P * 256;
  float* ymom = mom;       // [32]
  float* zmom = mom + 32;  // [16]

  if (tid < 128) { w0s[tid] = w0[tid]; w1s[tid] = w1[tid]; }
  __syncthreads();

  // ---- Phase 1: stats1 — y/y^2 sums (y = w0 @ s) -> ymom[32] ----
  {
    float sy[16], sy2[16];
#pragma unroll
    for (int c = 0; c < 16; ++c) { sy[c] = 0.f; sy2[c] = 0.f; }
    for (int p = blk * 256 + tid; p < NPT; p += stride) {
      const uint4 su = ((const uint4*)sB)[p];
      float s[8];
      unpack8(su, s);
#pragma unroll
      for (int c = 0; c < 16; ++c) {
        const float* wr = w0s + c * 8;
        float y = 0.f;
#pragma unroll
        for (int k = 0; k < 8; ++k) y += wr[k] * s[k];
        sy[c] += y;
        sy2[c] += y * y;
      }
    }
#pragma unroll
    for (int c = 0; c < 16; ++c) {
      for (int off = 32; off >= 1; off >>= 1) {
        sy[c] += __shfl_xor(sy[c], off);
        sy2[c] += __shfl_xor(sy2[c], off);
      }
    }
    const int wid = tid >> 6;
    if ((tid & 63) == 0) {
#pragma unroll
      for (int c = 0; c < 16; ++c) {
        red[wid * 32 + c] = sy[c];
        red[wid * 32 + 16 + c] = sy2[c];
      }
    }
    __syncthreads();
    if (tid < 32) {
      atomicAdd(&ymom[tid],
                red[tid] + red[32 + tid] + red[64 + tid] + red[96 + tid]);
    }
  }
  mini_barrier(&cnt[0]);

  // ---- Phase 2: stats2 — bn1 from ymom; z/z^2 -> zmom[16] ----
  if (tid < 16) {
    const float invN = 1.f / (float)NPT;
    const float mean = ymom[tid] * invN;
    const float var = ymom[16 + tid] * invN - mean * mean;
    const float a = g0[tid] * rsqrtf(var + EPSV);
    a1s[tid] = a;
    c1s[tid] = b0[tid] - mean * a;
  }
  __syncthreads();
  {
    float sz[8], sz2[8];
#pragma unroll
    for (int o = 0; o < 8; ++o) { sz[o] = 0.f; sz2[o] = 0.f; }
    for (int p = blk * 256 + tid; p < NPT; p += stride) {
      const uint4 su = ((const uint4*)sB)[p];
      float s[8];
      unpack8(su, s);
      float x1[16];
#pragma unroll
      for (int c = 0; c < 16; ++c) {
        const float* wr = w0s + c * 8;
        float y = 0.f;
#pragma unroll
        for (int k = 0; k < 8; ++k) y += wr[k] * s[k];
        x1[c] = fmaxf(a1s[c] * y + c1s[c], 0.f);
      }
#pragma unroll
      for (int o = 0; o < 8; ++o) {
        const float* wr = w1s + o * 16;
        float z = 0.f;
#pragma unroll
        for (int k = 0; k < 16; ++k) z += wr[k] * x1[k];
        sz[o] += z;
        sz2[o] += z * z;
      }
    }
#pragma unroll
    for (int o = 0; o < 8; ++o) {
      for (int off = 32; off >= 1; off >>= 1) {
        sz[o] += __shfl_xor(sz[o], off);
        sz2[o] += __shfl_xor(sz2[o], off);
      }
    }
    __syncthreads();  // red reuse guard
    const int wid = tid >> 6;
    if ((tid & 63) == 0) {
#pragma unroll
      for (int o = 0; o < 8; ++o) {
        red[wid * 16 + o] = sz[o];
        red[wid * 16 + 8 + o] = sz2[o];
      }
    }
    __syncthreads();
    if (tid < 16) {
      atomicAdd(&zmom[tid],
                red[tid] + red[16 + tid] + red[32 + tid] + red[48 + tid]);
    }
  }
  mini_barrier(&cnt[1]);

  // ---- Phase 3: final — bn2 from zmom; MLP + sigmoid -> out ----
  if (tid < 8) {
    const float invN = 1.f / (float)NPT;
    const float mean = zmom[tid] * invN;
    const float var = zmom[8 + tid] * invN - mean * mean;
    const float a = g1[tid] * rsqrtf(var + EPSV);
    a2s[tid] = a;
    c2s[tid] = b1[tid] - mean * a;
    wss[tid] = wsW[tid];
  }
  if (tid == 0) bssS = bs[0];
  __syncthreads();
  for (int p = blk * 256 + tid; p < NPT; p += stride) {
    const uint4 su = ((const uint4*)sB)[p];
    float s[8];
    unpack8(su, s);
    float x1[16];
#pragma unroll
    for (int c = 0; c < 16; ++c) {
      const float* wr = w0s + c * 8;
      float y = 0.f;
#pragma unroll
      for (int k = 0; k < 8; ++k) y += wr[k] * s[k];
      x1[c] = fmaxf(a1s[c] * y + c1s[c], 0.f);
    }
    float o = bssS;
#pragma unroll
    for (int oc = 0; oc < 8; ++oc) {
      const float* wr = w1s + oc * 16;
      float z = 0.f;
#pragma unroll
      for (int k = 0; k < 16; ++k) z += wr[k] * x1[k];
      const float x2 = fmaxf(a2s[oc] * z + c2s[oc], 0.f);
      o += wss[oc] * x2;
    }
    out[p] = 1.f / (1.f + expf(-o));
  }
}

// ---------------------------------------------------------------------------
extern "C" void kernel_launch(void* const* d_in, const int* in_sizes, int n_in,
                              void* d_out, int out_size, void* d_ws,
                              size_t ws_size, hipStream_t stream) {
  const float* feat = (const float*)d_in[0];  // [2,64,256,320]
  const float* grid = (const float*)d_in[1];  // [2,2304,320,2]
  const float* w0 = (const float*)d_in[2];    // [16,8]
  const float* g0 = (const float*)d_in[3];
  const float* b0 = (const float*)d_in[4];
  const float* w1 = (const float*)d_in[5];    // [8,16]
  const float* g1 = (const float*)d_in[6];
  const float* b1 = (const float*)d_in[7];
  const float* wsW = (const float*)d_in[8];   // [1,8]
  const float* bs = (const float*)d_in[9];    // [1]
  float* out = (float*)d_out;

  float* wsf = (float*)d_ws;  // ~45 MB
  unsigned short* featB = (unsigned short*)(wsf + OFF_FEATB);
  unsigned short* sB    = (unsigned short*)(wsf + OFF_SB);
  float* mom = wsf + OFF_MOM;
  int*   cnt = (int*)(wsf + OFF_CNT);

  k_transpose<<<Bc * (HWc / 64), 256, 0, stream>>>(feat, featB, mom);
  k_sample<<<NBLK_S, 256, 0, stream>>>(grid, featB, sB);
  k_post<<<NBLK_P, 256, 0, stream>>>(sB, w0, w1, g0, b0, g1, b1, wsW, bs,
                                     mom, cnt, out);
}

// Round 11
// 1279.983 us; speedup vs baseline: 1.4588x; 1.0060x over previous
//
#include <hip/hip_runtime.h>
#include <math.h>

// FeatureWeightNet: grid_sample(bilinear,border) -> group correlation (G=8) ->
// MLP(8->16->8->1) with per-batch BN stats -> sigmoid.
// R11: 3 dispatches; k_post's grid barrier rebuilt STORM-FREE.
// Storm history: R8 __threadfence = L2 wb+inv per block (FETCH 2 GB, 7x);
// R10 agent-scope ACQUIRE load = buffer_inv per block (FETCH 1.6 GB, 4x).
// Fix: barrier contains ZERO cache-maintenance ops —
//   release = __builtin_amdgcn_s_waitcnt(0) (wave-level drain; the ymom/zmom
//             atomicAdds belong to wave 0, same wave as tid 0) + RELAXED add;
//   spin + cross-barrier reads = RELAXED fetch_add(0) RMWs, which execute at
//             the Infinity Cache by atomicity bedrock — no buffer_inv needed.
// Only atomic-resident scalars (ymom[32]/zmom[16]) cross the barrier; bulk
// data (featB, sB) crosses kernel boundaries only.
// Co-residency: 512 blocks, __launch_bounds__(256,4) caps VGPR at 128 ->
// capacity >= 1024 blocks (R9 hang = no bound -> VGPR balloon -> deadlock).

constexpr int   Bc  = 2;
constexpr int   Cc  = 64;
constexpr int   Hc  = 256;
constexpr int   Wc  = 320;
constexpr int   NBc = 9;
constexpr int   HWc = Hc * Wc;            // 81920
constexpr int   NPIX = Bc * HWc;          // 163840
constexpr int   NPT  = Bc * NBc * HWc;    // 1474560 (= out_size)
constexpr float EPSV = 1e-5f;

constexpr int NBLK_S = NPIX / 32;         // 5120 sample blocks
constexpr int NBLK_P = 512;               // k_post blocks (<= half capacity)

// workspace layout in float units (~45 MB)
constexpr size_t OFF_FEATB = 0;                               // NHWC bf16: NPIX*64 ushort
constexpr size_t OFF_SB    = OFF_FEATB + (size_t)NPIX * 32;   // s bf16: NPT*8 ushort
constexpr size_t OFF_MOM   = OFF_SB + (size_t)NPT * 4;        // ymom[32], zmom[16]
constexpr size_t OFF_CNT   = OFF_MOM + 48;                    // 2 int counters

__device__ __forceinline__ unsigned short f2bf_rne(float v) {
  unsigned int u = __float_as_uint(v);
  unsigned int r = (u + 0x7fffu + ((u >> 16) & 1u)) >> 16;
  return (unsigned short)r;
}
__device__ __forceinline__ void unpack8(uint4 u, float f[8]) {
  f[0] = __uint_as_float(u.x << 16);
  f[1] = __uint_as_float(u.x & 0xffff0000u);
  f[2] = __uint_as_float(u.y << 16);
  f[3] = __uint_as_float(u.y & 0xffff0000u);
  f[4] = __uint_as_float(u.z << 16);
  f[5] = __uint_as_float(u.z & 0xffff0000u);
  f[6] = __uint_as_float(u.w << 16);
  f[7] = __uint_as_float(u.w & 0xffff0000u);
}

// read a float that lives at the coherence point (written by atomicAdd):
// relaxed RMW of +0.0f — guaranteed IC execution, no cache maintenance.
__device__ __forceinline__ float ic_read(float* p) {
  return __hip_atomic_fetch_add(p, 0.f, __ATOMIC_RELAXED,
                                __HIP_MEMORY_SCOPE_AGENT);
}

// Storm-free grid barrier. Caller guarantees this block's cross-barrier data
// was written via agent-scope atomicAdd BY WAVE 0 (so tid 0's s_waitcnt
// drains it). Unsigned compare: 0xAA ws-poison falls through on standalone
// profiling replays instead of hanging.
__device__ __forceinline__ void mini_barrier(int* cnt) {
  __syncthreads();
  if (threadIdx.x == 0) {
    __builtin_amdgcn_s_waitcnt(0);          // wave-0 atomics ack'd at IC
    __atomic_signal_fence(__ATOMIC_SEQ_CST);
    __hip_atomic_fetch_add(cnt, 1, __ATOMIC_RELAXED, __HIP_MEMORY_SCOPE_AGENT);
    while ((unsigned)__hip_atomic_fetch_add(cnt, 0, __ATOMIC_RELAXED,
                                            __HIP_MEMORY_SCOPE_AGENT) <
           (unsigned)NBLK_P) {
      __builtin_amdgcn_s_sleep(8);
    }
    __atomic_signal_fence(__ATOMIC_SEQ_CST);
  }
  __syncthreads();
}

// ---------------------------------------------------------------------------
// K0: NCHW fp32 -> NHWC bf16 transpose; block 0 zeroes moment + counter slots.
__global__ __launch_bounds__(256) void k_transpose(
    const float* __restrict__ feat, unsigned short* __restrict__ featB,
    float* __restrict__ mom) {
  if (blockIdx.x == 0 && threadIdx.x < 56) mom[threadIdx.x] = 0.f;
  __shared__ float lds[64][65];
  const int tid  = threadIdx.x;
  const int b    = blockIdx.x / (HWc / 64);
  const int tile = blockIdx.x % (HWc / 64);
  const int hw0  = tile * 64;
  const int p    = tid & 63;
  const int ty   = tid >> 6;  // 0..3

  const float* src = feat + (size_t)b * Cc * HWc + hw0 + p;
#pragma unroll
  for (int c0 = 0; c0 < 64; c0 += 4) {
    lds[c0 + ty][p] = src[(size_t)(c0 + ty) * HWc];
  }
  __syncthreads();
  const int ch = tid & 63;
  unsigned short* dst = featB + ((size_t)b * HWc + hw0) * 64 + ch;
#pragma unroll
  for (int p0 = 0; p0 < 64; p0 += 4) {
    dst[(size_t)(p0 + ty) * 64] = f2bf_rne(lds[ch][p0 + ty]);
  }
}

// ---------------------------------------------------------------------------
// K1: grid sample + group correlation.  VERBATIM R7 (79 us, 3.7 TB/s proven).
__global__ __launch_bounds__(256) void k_sample(
    const float* __restrict__ grid, const unsigned short* __restrict__ featB,
    unsigned short* __restrict__ sOut) {
  const int tid = threadIdx.x;
  const int cid = blockIdx.x * 32 + (tid >> 3);  // pixel id in [0, NPIX)
  const int j   = tid & 7;                       // group
  const int b   = cid / HWc;
  const int hw  = cid - b * HWc;
  const int h   = hw / Wc;
  const int w   = hw - h * Wc;

  const uint4* fbAll = (const uint4*)featB;
  const uint4 ur = fbAll[(size_t)cid * 8 + j];
  float r[8];
  unpack8(ur, r);

  const uint4* fb = fbAll + (size_t)b * HWc * 8;

#pragma unroll 3
  for (int n = 0; n < NBc; ++n) {
    const size_t gi = ((((size_t)b * NBc + n) * Hc + h) * Wc + w) * 2;
    const float2 g2 = *(const float2*)(grid + gi);
    float ix = ((g2.x + 1.f) * (float)Wc - 1.f) * 0.5f;
    float iy = ((g2.y + 1.f) * (float)Hc - 1.f) * 0.5f;
    ix = fminf(fmaxf(ix, 0.f), (float)(Wc - 1));
    iy = fminf(fmaxf(iy, 0.f), (float)(Hc - 1));
    const float x0f = floorf(ix), y0f = floorf(iy);
    const float fx = ix - x0f, fy = iy - y0f;
    const int x0 = (int)x0f, y0 = (int)y0f;
    const int x1 = min(x0 + 1, Wc - 1), y1 = min(y0 + 1, Hc - 1);
    const float w00 = (1.f - fx) * (1.f - fy);
    const float w01 = fx * (1.f - fy);
    const float w10 = (1.f - fx) * fy;
    const float w11 = fx * fy;

    const uint4 u00 = fb[(size_t)(y0 * Wc + x0) * 8 + j];
    const uint4 u01 = fb[(size_t)(y0 * Wc + x1) * 8 + j];
    const uint4 u10 = fb[(size_t)(y1 * Wc + x0) * 8 + j];
    const uint4 u11 = fb[(size_t)(y1 * Wc + x1) * 8 + j];
    float a[8], c[8], d[8], e[8];
    unpack8(u00, a);
    unpack8(u01, c);
    unpack8(u10, d);
    unpack8(u11, e);

    float s = 0.f;
#pragma unroll
    for (int k = 0; k < 8; ++k) {
      s += (w00 * a[k] + w01 * c[k] + w10 * d[k] + w11 * e[k]) * r[k];
    }
    s *= 0.125f;  // mean over C/G = 8

    const size_t pt = ((size_t)b * NBc + n) * HWc + hw;
    sOut[pt * 8 + j] = f2bf_rne(s);
  }
}

// ---------------------------------------------------------------------------
// K2: fused stats1 / stats2 / final with two storm-free mini-barriers.
__global__ __launch_bounds__(256, 4) void k_post(
    const unsigned short* __restrict__ sB, const float* __restrict__ w0,
    const float* __restrict__ w1, const float* __restrict__ g0,
    const float* __restrict__ b0, const float* __restrict__ g1,
    const float* __restrict__ b1, const float* __restrict__ wsW,
    const float* __restrict__ bs, float* __restrict__ mom,
    int* __restrict__ cnt, float* __restrict__ out) {
  __shared__ float w0s[128], w1s[128], a1s[16], c1s[16], a2s[8], c2s[8], wss[8];
  __shared__ float bssS;
  __shared__ float red[128];
  const int tid = threadIdx.x;
  const int blk = blockIdx.x;
  const int stride = NBLK_P * 256;
  float* ymom = mom;       // [32]
  float* zmom = mom + 32;  // [16]

  if (tid < 128) { w0s[tid] = w0[tid]; w1s[tid] = w1[tid]; }
  __syncthreads();

  // ---- Phase 1: stats1 — y/y^2 sums (y = w0 @ s) -> ymom[32] ----
  {
    float sy[16], sy2[16];
#pragma unroll
    for (int c = 0; c < 16; ++c) { sy[c] = 0.f; sy2[c] = 0.f; }
    for (int p = blk * 256 + tid; p < NPT; p += stride) {
      const uint4 su = ((const uint4*)sB)[p];
      float s[8];
      unpack8(su, s);
#pragma unroll
      for (int c = 0; c < 16; ++c) {
        const float* wr = w0s + c * 8;
        float y = 0.f;
#pragma unroll
        for (int k = 0; k < 8; ++k) y += wr[k] * s[k];
        sy[c] += y;
        sy2[c] += y * y;
      }
    }
#pragma unroll
    for (int c = 0; c < 16; ++c) {
      for (int off = 32; off >= 1; off >>= 1) {
        sy[c] += __shfl_xor(sy[c], off);
        sy2[c] += __shfl_xor(sy2[c], off);
      }
    }
    const int wid = tid >> 6;
    if ((tid & 63) == 0) {
#pragma unroll
      for (int c = 0; c < 16; ++c) {
        red[wid * 32 + c] = sy[c];
        red[wid * 32 + 16 + c] = sy2[c];
      }
    }
    __syncthreads();
    if (tid < 32) {  // wave 0: its atomics are drained by tid 0's s_waitcnt
      atomicAdd(&ymom[tid],
                red[tid] + red[32 + tid] + red[64 + tid] + red[96 + tid]);
    }
  }
  mini_barrier(&cnt[0]);

  // ---- Phase 2: stats2 — bn1 from ymom (IC reads); z/z^2 -> zmom[16] ----
  if (tid < 16) {
    const float invN = 1.f / (float)NPT;
    const float sy = ic_read(&ymom[tid]);
    const float sy2 = ic_read(&ymom[16 + tid]);
    const float mean = sy * invN;
    const float var = sy2 * invN - mean * mean;
    const float a = g0[tid] * rsqrtf(var + EPSV);
    a1s[tid] = a;
    c1s[tid] = b0[tid] - mean * a;
  }
  __syncthreads();
  {
    float sz[8], sz2[8];
#pragma unroll
    for (int o = 0; o < 8; ++o) { sz[o] = 0.f; sz2[o] = 0.f; }
    for (int p = blk * 256 + tid; p < NPT; p += stride) {
      const uint4 su = ((const uint4*)sB)[p];
      float s[8];
      unpack8(su, s);
      float x1[16];
#pragma unroll
      for (int c = 0; c < 16; ++c) {
        const float* wr = w0s + c * 8;
        float y = 0.f;
#pragma unroll
        for (int k = 0; k < 8; ++k) y += wr[k] * s[k];
        x1[c] = fmaxf(a1s[c] * y + c1s[c], 0.f);
      }
#pragma unroll
      for (int o = 0; o < 8; ++o) {
        const float* wr = w1s + o * 16;
        float z = 0.f;
#pragma unroll
        for (int k = 0; k < 16; ++k) z += wr[k] * x1[k];
        sz[o] += z;
        sz2[o] += z * z;
      }
    }
#pragma unroll
    for (int o = 0; o < 8; ++o) {
      for (int off = 32; off >= 1; off >>= 1) {
        sz[o] += __shfl_xor(sz[o], off);
        sz2[o] += __shfl_xor(sz2[o], off);
      }
    }
    __syncthreads();  // red reuse guard
    const int wid = tid >> 6;
    if ((tid & 63) == 0) {
#pragma unroll
      for (int o = 0; o < 8; ++o) {
        red[wid * 16 + o] = sz[o];
        red[wid * 16 + 8 + o] = sz2[o];
      }
    }
    __syncthreads();
    if (tid < 16) {  // wave 0 again
      atomicAdd(&zmom[tid],
                red[tid] + red[16 + tid] + red[32 + tid] + red[48 + tid]);
    }
  }
  mini_barrier(&cnt[1]);

  // ---- Phase 3: final — bn2 from zmom (IC reads); MLP + sigmoid -> out ----
  if (tid < 8) {
    const float invN = 1.f / (float)NPT;
    const float szs = ic_read(&zmom[tid]);
    const float szs2 = ic_read(&zmom[8 + tid]);
    const float mean = szs * invN;
    const float var = szs2 * invN - mean * mean;
    const float a = g1[tid] * rsqrtf(var + EPSV);
    a2s[tid] = a;
    c2s[tid] = b1[tid] - mean * a;
    wss[tid] = wsW[tid];
  }
  if (tid == 0) bssS = bs[0];
  __syncthreads();
  for (int p = blk * 256 + tid; p < NPT; p += stride) {
    const uint4 su = ((const uint4*)sB)[p];
    float s[8];
    unpack8(su, s);
    float x1[16];
#pragma unroll
    for (int c = 0; c < 16; ++c) {
      const float* wr = w0s + c * 8;
      float y = 0.f;
#pragma unroll
      for (int k = 0; k < 8; ++k) y += wr[k] * s[k];
      x1[c] = fmaxf(a1s[c] * y + c1s[c], 0.f);
    }
    float o = bssS;
#pragma unroll
    for (int oc = 0; oc < 8; ++oc) {
      const float* wr = w1s + oc * 16;
      float z = 0.f;
#pragma unroll
      for (int k = 0; k < 16; ++k) z += wr[k] * x1[k];
      const float x2 = fmaxf(a2s[oc] * z + c2s[oc], 0.f);
      o += wss[oc] * x2;
    }
    out[p] = 1.f / (1.f + expf(-o));
  }
}

// ---------------------------------------------------------------------------
extern "C" void kernel_launch(void* const* d_in, const int* in_sizes, int n_in,
                              void* d_out, int out_size, void* d_ws,
                              size_t ws_size, hipStream_t stream) {
  const float* feat = (const float*)d_in[0];  // [2,64,256,320]
  const float* grid = (const float*)d_in[1];  // [2,2304,320,2]
  const float* w0 = (const float*)d_in[2];    // [16,8]
  const float* g0 = (const float*)d_in[3];
  const float* b0 = (const float*)d_in[4];
  const float* w1 = (const float*)d_in[5];    // [8,16]
  const float* g1 = (const float*)d_in[6];
  const float* b1 = (const float*)d_in[7];
  const float* wsW = (const float*)d_in[8];   // [1,8]
  const float* bs = (const float*)d_in[9];    // [1]
  float* out = (float*)d_out;

  float* wsf = (float*)d_ws;  // ~45 MB
  unsigned short* featB = (unsigned short*)(wsf + OFF_FEATB);
  unsigned short* sB    = (unsigned short*)(wsf + OFF_SB);
  float* mom = wsf + OFF_MOM;
  int*   cnt = (int*)(wsf + OFF_CNT);

  k_transpose<<<Bc * (HWc / 64), 256, 0, stream>>>(feat, featB, mom);
  k_sample<<<NBLK_S, 256, 0, stream>>>(grid, featB, sB);
  k_post<<<NBLK_P, 256, 0, stream>>>(sB, w0, w1, g0, b0, g1, b1, wsW, bs,
                                     mom, cnt, out);
}